// Round 1
// baseline (655.962 us; speedup 1.0000x reference)
//
#include <hip/hip_runtime.h>
#include <math.h>

// Real spherical harmonics, l_max = 8, output [N, 81] f32.
// v2: persistent single-wave blocks (7/CU, LDS-limited), grid-stride over
// 64-point tiles. No __syncthreads (single wave per block -> in-order DS pipe
// + compiler lgkmcnt ordering are sufficient), so the per-tile global stores
// are NEVER drained inside the loop: next tile's input loads are issued
// BEFORE this tile's stores, keeping the vmcnt wait for them at vmcnt(21)
// instead of vmcnt(0). Store drain happens once per persistent block
// (~17 tiles) instead of once per tile.

namespace {

constexpr double csqrt(double x) {
    double g = x > 1.0 ? x : 1.0;
    for (int i = 0; i < 200; ++i) g = 0.5 * (g + x / g);
    return g;
}
constexpr double cfact(int n) {
    double r = 1.0;
    for (int i = 2; i <= n; ++i) r *= (double)i;
    return r;
}
constexpr double PI_D = 3.14159265358979323846264338327950288;

constexpr float coefv(int l, int m) {
    const int am = m < 0 ? -m : m;
    const double k = csqrt((2.0 * l + 1.0) / (4.0 * PI_D) * cfact(l - am) / cfact(l + am));
    const double s2 = 1.4142135623730950488016887242097;
    return (float)((m == 0 ? 1.0 : s2) * k);
}

struct CoefTab { float v[81]; };
constexpr CoefTab make_tab() {
    CoefTab t{};
    for (int l = 0; l <= 8; ++l)
        for (int m = -l; m <= l; ++m)
            t.v[l * l + l + m] = coefv(l, m);
    return t;
}
constexpr CoefTab COEF = make_tab();  // compile-time; folds to literals in unrolled code

} // namespace

#define LMAX 8
#define NCOL 81
#define PTS 64
#define TILE_FLOATS (PTS * NCOL)    // 5184 floats = 20736 B LDS -> 7 blocks/CU
#define TILE_F4 (TILE_FLOATS / 4)   // 1296 float4 per tile

__global__ __launch_bounds__(PTS)
void sh_kernel(const float* __restrict__ ct_in, const float* __restrict__ phi_in,
               float* __restrict__ out, int n) {
    __shared__ __align__(16) float lds[TILE_FLOATS];
    const int lane = threadIdx.x;                    // 0..63
    const int ntiles = (n + PTS - 1) / PTS;
    const long long total_f4 = ((long long)n * NCOL) / 4;
    const long long stride = gridDim.x;

    long long tile = blockIdx.x;
    if (tile >= ntiles) return;

    // Prefetch first tile's inputs (clamped; clamp only matters for a ragged
    // final tile, which this problem's N=2e6 never produces).
    long long cidx = tile * PTS + lane;
    if (cidx >= n) cidx = (long long)n - 1;
    float ct  = ct_in[cidx];
    float phi = phi_in[cidx];

    while (tile < ntiles) {
        // ---- compute this tile into LDS (row stride 81 words: odd -> conflict-free)
        const float st = sqrtf(fmaxf(1.0f - ct * ct, 0.0f));
        float sp, cp;
        __sincosf(phi, &sp, &cp);

        float* row = lds + lane * NCOL;
        float pmm = 1.0f;                            // P(m,m)
        float cm = 1.0f;                             // cos(m*phi)
        float sm = 0.0f;                             // sin(m*phi)
#pragma unroll
        for (int m = 0; m <= LMAX; ++m) {
            if (m > 0) {
                pmm *= st * (float)(2 * m - 1);      // P(m,m) = P(m-1,m-1)*st*(2m-1)
                const float cn = cm * cp - sm * sp;
                const float sn = sm * cp + cm * sp;
                cm = cn; sm = sn;
            }
            {   // l = m
                const int b = m * m + m;
                if (m == 0) {
                    row[b] = COEF.v[b] * pmm;
                } else {
                    row[b + m] = COEF.v[b + m] * pmm * cm;
                    row[b - m] = COEF.v[b - m] * pmm * sm;
                }
            }
            if (m < LMAX) {
                float p_prev = pmm;
                float p_cur = ct * (float)(2 * m + 1) * pmm;   // P(m+1,m)
                {
                    const int l = m + 1;
                    const int b = l * l + l;
                    if (m == 0) {
                        row[b] = COEF.v[b] * p_cur;
                    } else {
                        row[b + m] = COEF.v[b + m] * p_cur * cm;
                        row[b - m] = COEF.v[b - m] * p_cur * sm;
                    }
                }
#pragma unroll
                for (int l = m + 2; l <= LMAX; ++l) {
                    const float inv = 1.0f / (float)(l - m);   // compile-time constant
                    const float p_next = ((float)(2 * l - 1) * ct * p_cur
                                          - (float)(l + m - 1) * p_prev) * inv;
                    p_prev = p_cur; p_cur = p_next;
                    const int b = l * l + l;
                    if (m == 0) {
                        row[b] = COEF.v[b] * p_cur;
                    } else {
                        row[b + m] = COEF.v[b + m] * p_cur * cm;
                        row[b - m] = COEF.v[b - m] * p_cur * sm;
                    }
                }
            }
        }

        // ---- prefetch NEXT tile's inputs BEFORE issuing this tile's stores.
        // vmcnt decrements in issue order: because these loads are older than
        // the 21 stores below, next iteration's wait for them is vmcnt(21),
        // not vmcnt(0) -- the store queue never drains inside the loop.
        const long long ntile = tile + stride;
        {
            long long nidx = ntile * PTS + lane;
            if (nidx >= n) nidx = (long long)n - 1;  // clamp (also covers ntile >= ntiles)
            ct  = ct_in[nidx];
            phi = phi_in[nidx];
        }

        // Single-wave block: DS ops execute in order per wave and the compiler
        // inserts lgkmcnt waits for the may-alias write->read; wave_barrier
        // just pins the scheduling order. No s_barrier, no vmcnt(0).
        __builtin_amdgcn_wave_barrier();

        // ---- coalesced tile write: 1296 contiguous float4 (20 rounds + 16-lane tail)
        float4* __restrict__ outv = (float4*)out + tile * (long long)TILE_F4;
        const float4* lv = (const float4*)lds;
        const long long base = tile * (long long)TILE_F4;
        if (base + TILE_F4 <= total_f4) {            // full tile (always, for N%64==0)
#pragma unroll
            for (int j = 0; j < 20; ++j) outv[j * 64 + lane] = lv[j * 64 + lane];
            if (lane < 16) outv[20 * 64 + lane] = lv[20 * 64 + lane];
        } else {                                     // ragged final tile (generic n)
#pragma unroll
            for (int j = 0; j < 21; ++j) {
                const int e = j * 64 + lane;
                if (e < TILE_F4 && base + e < total_f4) outv[e] = lv[e];
            }
        }

        __builtin_amdgcn_wave_barrier();             // keep next tile's ds_writes behind these ds_reads
        tile = ntile;
    }
}

extern "C" void kernel_launch(void* const* d_in, const int* in_sizes, int n_in,
                              void* d_out, int out_size, void* d_ws, size_t ws_size,
                              hipStream_t stream) {
    const float* ct  = (const float*)d_in[1];
    const float* phi = (const float*)d_in[2];
    float* out = (float*)d_out;
    const int n = in_sizes[1];
    const int ntiles = (n + PTS - 1) / PTS;
    // 7 blocks/CU (LDS-limited: 160 KiB / 20736 B = 7) x 256 CUs, persistent.
    int blocks = 7 * 256;
    if (blocks > ntiles) blocks = ntiles;
    sh_kernel<<<blocks, PTS, 0, stream>>>(ct, phi, out, n);
}

// Round 2
// 651.773 us; speedup vs baseline: 1.0064x; 1.0064x over previous
//
#include <hip/hip_runtime.h>
#include <math.h>

// Real spherical harmonics, l_max = 8, output [N, 81] f32.
// v3: v2's persistent single-wave blocks + NONTEMPORAL stores.
// Theory: the kernel's effective write BW (~2.8 TB/s) is far below what every
// issue-rate/occupancy model predicts (saturation), so the limiter must be on
// the write path itself: compiler-default stores allocate dirty lines in
// L2 + 256 MiB Infinity Cache; a 648 MB write-once stream thrashes the MALL
// (allocate->evict on every line). __builtin_nontemporal_store marks the
// stream as non-cached (nt/sc bits), letting writes stream to HBM the way the
// runtime's fillBuffer (6.2 TB/s on this same buffer) does.

namespace {

constexpr double csqrt(double x) {
    double g = x > 1.0 ? x : 1.0;
    for (int i = 0; i < 200; ++i) g = 0.5 * (g + x / g);
    return g;
}
constexpr double cfact(int n) {
    double r = 1.0;
    for (int i = 2; i <= n; ++i) r *= (double)i;
    return r;
}
constexpr double PI_D = 3.14159265358979323846264338327950288;

constexpr float coefv(int l, int m) {
    const int am = m < 0 ? -m : m;
    const double k = csqrt((2.0 * l + 1.0) / (4.0 * PI_D) * cfact(l - am) / cfact(l + am));
    const double s2 = 1.4142135623730950488016887242097;
    return (float)((m == 0 ? 1.0 : s2) * k);
}

struct CoefTab { float v[81]; };
constexpr CoefTab make_tab() {
    CoefTab t{};
    for (int l = 0; l <= 8; ++l)
        for (int m = -l; m <= l; ++m)
            t.v[l * l + l + m] = coefv(l, m);
    return t;
}
constexpr CoefTab COEF = make_tab();  // compile-time; folds to literals

typedef float f4 __attribute__((ext_vector_type(4)));

} // namespace

#define LMAX 8
#define NCOL 81
#define PTS 64
#define TILE_FLOATS (PTS * NCOL)    // 5184 floats = 20736 B LDS -> 7 blocks/CU
#define TILE_F4 (TILE_FLOATS / 4)   // 1296 float4 per tile

__global__ __launch_bounds__(PTS)
void sh_kernel(const float* __restrict__ ct_in, const float* __restrict__ phi_in,
               float* __restrict__ out, int n) {
    __shared__ __align__(16) float lds[TILE_FLOATS];
    const int lane = threadIdx.x;                    // 0..63
    const int ntiles = (n + PTS - 1) / PTS;
    const long long total_f4 = ((long long)n * NCOL) / 4;
    const long long stride = gridDim.x;

    long long tile = blockIdx.x;
    if (tile >= ntiles) return;

    // Prefetch first tile's inputs (clamped; only matters for ragged tail).
    long long cidx = tile * PTS + lane;
    if (cidx >= n) cidx = (long long)n - 1;
    float ct  = __builtin_nontemporal_load(ct_in + cidx);
    float phi = __builtin_nontemporal_load(phi_in + cidx);

    while (tile < ntiles) {
        // ---- compute this tile into LDS (row stride 81 words: odd -> conflict-free)
        const float st = sqrtf(fmaxf(1.0f - ct * ct, 0.0f));
        float sp, cp;
        __sincosf(phi, &sp, &cp);

        float* row = lds + lane * NCOL;
        float pmm = 1.0f;                            // P(m,m)
        float cm = 1.0f;                             // cos(m*phi)
        float sm = 0.0f;                             // sin(m*phi)
#pragma unroll
        for (int m = 0; m <= LMAX; ++m) {
            if (m > 0) {
                pmm *= st * (float)(2 * m - 1);      // P(m,m) = P(m-1,m-1)*st*(2m-1)
                const float cn = cm * cp - sm * sp;
                const float sn = sm * cp + cm * sp;
                cm = cn; sm = sn;
            }
            {   // l = m
                const int b = m * m + m;
                if (m == 0) {
                    row[b] = COEF.v[b] * pmm;
                } else {
                    row[b + m] = COEF.v[b + m] * pmm * cm;
                    row[b - m] = COEF.v[b - m] * pmm * sm;
                }
            }
            if (m < LMAX) {
                float p_prev = pmm;
                float p_cur = ct * (float)(2 * m + 1) * pmm;   // P(m+1,m)
                {
                    const int l = m + 1;
                    const int b = l * l + l;
                    if (m == 0) {
                        row[b] = COEF.v[b] * p_cur;
                    } else {
                        row[b + m] = COEF.v[b + m] * p_cur * cm;
                        row[b - m] = COEF.v[b - m] * p_cur * sm;
                    }
                }
#pragma unroll
                for (int l = m + 2; l <= LMAX; ++l) {
                    const float inv = 1.0f / (float)(l - m);   // compile-time constant
                    const float p_next = ((float)(2 * l - 1) * ct * p_cur
                                          - (float)(l + m - 1) * p_prev) * inv;
                    p_prev = p_cur; p_cur = p_next;
                    const int b = l * l + l;
                    if (m == 0) {
                        row[b] = COEF.v[b] * p_cur;
                    } else {
                        row[b + m] = COEF.v[b + m] * p_cur * cm;
                        row[b - m] = COEF.v[b - m] * p_cur * sm;
                    }
                }
            }
        }

        // ---- prefetch NEXT tile's inputs before issuing this tile's stores,
        // so the wait for them never drains the store queue.
        const long long ntile = tile + stride;
        {
            long long nidx = ntile * PTS + lane;
            if (nidx >= n) nidx = (long long)n - 1;  // clamp (covers ntile >= ntiles)
            ct  = __builtin_nontemporal_load(ct_in + nidx);
            phi = __builtin_nontemporal_load(phi_in + nidx);
        }

        // Single-wave block: DS pipe is in-order per wave; compiler inserts the
        // lgkmcnt waits for the write->read. No s_barrier, no vmcnt(0).
        __builtin_amdgcn_wave_barrier();

        // ---- coalesced tile write: 1296 contiguous float4, NONTEMPORAL
        f4* __restrict__ outv = (f4*)out + tile * (long long)TILE_F4;
        const f4* lv = (const f4*)lds;
        const long long base = tile * (long long)TILE_F4;
        if (base + TILE_F4 <= total_f4) {            // full tile (always for N%64==0)
#pragma unroll
            for (int j = 0; j < 20; ++j) {
                const int e = j * 64 + lane;
                __builtin_nontemporal_store(lv[e], &outv[e]);
            }
            if (lane < 16) {
                const int e = 20 * 64 + lane;
                __builtin_nontemporal_store(lv[e], &outv[e]);
            }
        } else {                                     // ragged final tile (generic n)
#pragma unroll
            for (int j = 0; j < 21; ++j) {
                const int e = j * 64 + lane;
                if (e < TILE_F4 && base + e < total_f4)
                    __builtin_nontemporal_store(lv[e], &outv[e]);
            }
        }

        __builtin_amdgcn_wave_barrier();             // keep next tile's ds_writes behind these ds_reads
        tile = ntile;
    }
}

extern "C" void kernel_launch(void* const* d_in, const int* in_sizes, int n_in,
                              void* d_out, int out_size, void* d_ws, size_t ws_size,
                              hipStream_t stream) {
    const float* ct  = (const float*)d_in[1];
    const float* phi = (const float*)d_in[2];
    float* out = (float*)d_out;
    const int n = in_sizes[1];
    const int ntiles = (n + PTS - 1) / PTS;
    // 7 blocks/CU (LDS-limited: 160 KiB / 20736 B = 7) x 256 CUs, persistent.
    int blocks = 7 * 256;
    if (blocks > ntiles) blocks = ntiles;
    sh_kernel<<<blocks, PTS, 0, stream>>>(ct, phi, out, n);
}